// Round 19
// baseline (426.640 us; speedup 1.0000x reference)
//
#include <hip/hip_runtime.h>
#include <cstdint>
#include <cstddef>

#define NTR 16384
#define NQR 4096
#define NROW 20480
#define DF  128
#define NCL 19

typedef unsigned short u16;
typedef unsigned int u32;
typedef __attribute__((ext_vector_type(8))) short bf16x8;
typedef __attribute__((ext_vector_type(16))) float f32x16;

// ---- workspace layout (bytes) ----
#define OFF_RN    (size_t)0                  // float[20480]
#define OFF_QEXT  (size_t)81920              // u16[20480][144]
#define OFF_CEXT  (size_t)5980160            // u16[16384][144] (negated + hb dims)
#define OFF_FSN   (size_t)10698752           // u16[20480][96]
#define OFF_NBRT  (size_t)18563072           // int[16384][20]
#define OFF_NBRQ  (size_t)19873792           // int[4096][20]
#define OFF_HIST  (size_t)20201472           // int[2][2][19][32]
#define OFF_COND  (size_t)20211200           // float[2][2][19][32]
#define OFF_PRIOR (size_t)20220928           // float[19]
#define WS_NEEDED (size_t)20221008

// separately-rounded multiply (asm barrier blocks mul+add -> fma contraction)
__device__ __forceinline__ float mulr(float a, float b) {
  float m = a * b;
  asm volatile("" : "+v"(m));
  return m;
}

__device__ __forceinline__ u16 bf16_rne(float x) {
  union { float f; unsigned u; } v; v.f = x;
  unsigned r = (v.u + 0x7fffu + ((v.u >> 16) & 1u)) >> 16;
  return (u16)r;
}
__device__ __forceinline__ float bf16_f32(u16 h) {
  union { unsigned u; float f; } v; v.u = ((unsigned)h) << 16;
  return v.f;
}

__device__ __forceinline__ void gload_lds16(const void* g, void* lds) {
  __builtin_amdgcn_global_load_lds(
      (const __attribute__((address_space(1))) unsigned int*)g,
      (__attribute__((address_space(3))) unsigned int*)lds, 16, 0, 0);
}

// ---------------- row norms: exact reference realization (no FMA) ------------
__global__ __launch_bounds__(256) void norms_kernel(const float* __restrict__ train,
                                                    const float* __restrict__ feat,
                                                    float* __restrict__ rn) {
  int i = blockIdx.x * 256 + threadIdx.x;  // 80 blocks -> 20480
  const float* src = (i < NTR) ? (train + (size_t)i * DF) : (feat + (size_t)(i - NTR) * DF);
  float s = 0.0f;
  for (int k = 0; k < DF; ++k) {
    float x = src[k];
    s = s + mulr(x, x);
  }
  rn[i] = s;
}

// ---------------- ext: bf16 rows + metric K-extension (r12 form) -------------
// qext[row][144]: [bf16(x_k)]*128, dim128=1.0, dim129=1.0, rest 0
// cext[c][144]:   [bf16(-x_k)]*128, dim128=hb_hi, dim129=hb_lo, rest 0
// where hb = 0.5*rn[c] + 256  ->  mfma(C,Q) = 256 + hb - dot  (positive metric)
__global__ __launch_bounds__(256) void ext_kernel(const float* __restrict__ train,
                                                  const float* __restrict__ feat,
                                                  const float* __restrict__ rn,
                                                  u16* __restrict__ qext,
                                                  u16* __restrict__ cext) {
  int row = blockIdx.x * 2 + (threadIdx.x >> 7);  // 10240 blocks -> 20480
  int k = threadIdx.x & 127;
  const float* srcp = (row < NTR) ? (train + (size_t)row * DF) : (feat + (size_t)(row - NTR) * DF);
  float x = srcp[k];
  u16 b = bf16_rne(x);
  qext[(size_t)row * 144 + k] = b;
  if (row < NTR) cext[(size_t)row * 144 + k] = (u16)(b ^ 0x8000u);
  if (k < 16) {
    qext[(size_t)row * 144 + 128 + k] = (k < 2) ? (u16)0x3F80 : (u16)0;
    if (row < NTR) {
      float hbf = 0.5f * rn[row] + 256.0f;
      u16 hi = bf16_rne(hbf);
      u16 lo = bf16_rne(hbf - bf16_f32(hi));
      cext[(size_t)row * 144 + 128 + k] = (k == 0) ? hi : ((k == 1) ? lo : (u16)0);
    }
  }
}

// ---------------- FILTER: swapped 32x32x16 MFMA, 1 q-subtile/wave ------------
// r19 = r12's exact config (best measured 236us): 4 slices of 4096 cands,
// grid 1280, 64 tiles/block, dbuf 36.9KB, 12-bit packed keys, bitonic merge.
__global__ __launch_bounds__(256, 4) void filter_kernel(const u16* __restrict__ qext,
                                                        const u16* __restrict__ cext,
                                                        u16* __restrict__ fsn) {
  __shared__ __align__(16) char smem[36864];  // cbuf[2]:16KB, hbuf[2]:2KB
  const int bid = blockIdx.x;
  const int slice = bid & 3, rowblk = bid >> 2;
  const int grow0 = rowblk * 64;
  const int cslice0 = slice * 4096;
  const int tid = threadIdx.x;
  const int wave = tid >> 6, lane = tid & 63;
  const int wq = wave >> 1, wc = wave & 1;
  const int l31 = lane & 31, h = lane >> 5;
  const char* qb = (const char*)qext;
  const char* cbg = (const char*)cext;

  // q fragments in registers: 9 ksteps for this wave's 32-row q-subtile
  bf16x8 qf[9];
  const int qrow = grow0 + wq * 32 + l31;
#pragma unroll
  for (int ks = 0; ks < 8; ++ks)
    qf[ks] = *(const bf16x8*)(qb + (size_t)qrow * 288 + ks * 32 + h * 16);
  qf[8] = *(const bf16x8*)(qb + (size_t)qrow * 288 + 256 + h * 16);

  u32 sd[16];
#pragma unroll
  for (int t = 0; t < 16; ++t) sd[t] = 0x7F7FFFFFu;
  float th_f = __uint_as_float(0x7F7FF000u);

  // incremental per-thread staging source pointers (advance 64*288 B per tile)
  const char* srcA[4];
#pragma unroll
  for (int j = 0; j < 4; ++j) {
    int I = wave + 4 * j;
    int G = I * 64 + lane;
    int r = G >> 4, g = G & 15;
    srcA[j] = cbg + (size_t)(cslice0 + r) * 288 + ((g << 4) ^ ((r & 7) << 4));
  }
  const char* srcH = nullptr;
  if (wave < 2) {
    int GG = wave * 64 + lane;
    int r = GG >> 1, half = GG & 1;
    srcH = cbg + (size_t)(cslice0 + r) * 288 + 256 + half * 16;
  }

  auto STAGE = [&](int buf) {
    char* cb = smem + buf * 16384;
#pragma unroll
    for (int j = 0; j < 4; ++j) {
      int I = wave + 4 * j;
      gload_lds16(srcA[j], cb + I * 1024);
      srcA[j] += 64 * 288;
    }
    if (wave < 2) {
      gload_lds16(srcH, smem + 32768 + buf * 2048 + wave * 1024);
      srcH += 64 * 288;
    }
  };

  STAGE(0);
  __syncthreads();

  const int crow = wc * 32 + l31;
  for (int nt = 0; nt < 64; ++nt) {
    const int cur = nt & 1;
    if (nt < 63) STAGE(cur ^ 1);

    const char* cbp = smem + cur * 16384 + crow * 256;
    const char* hbp = smem + 32768 + cur * 2048 + crow * 32 + h * 16;
    f32x16 acc = {0.f,0.f,0.f,0.f,0.f,0.f,0.f,0.f,0.f,0.f,0.f,0.f,0.f,0.f,0.f,0.f};
#pragma unroll
    for (int ks = 0; ks < 8; ++ks) {
      bf16x8 cf = *(const bf16x8*)(cbp + ((ks * 32 + h * 16) ^ ((crow & 7) << 4)));
      acc = __builtin_amdgcn_mfma_f32_32x32x16_bf16(cf, qf[ks], acc, 0, 0, 0);
    }
    {
      bf16x8 cf = *(const bf16x8*)hbp;
      acc = __builtin_amdgcn_mfma_f32_32x32x16_bf16(cf, qf[8], acc, 0, 0, 0);
    }

    // ---- float guard first (saves key packing on non-triggered tiles) ----
    float f01 = fminf(acc[0], acc[1]),   f23 = fminf(acc[2], acc[3]);
    float f45 = fminf(acc[4], acc[5]),   f67 = fminf(acc[6], acc[7]);
    float f89 = fminf(acc[8], acc[9]),   fab = fminf(acc[10], acc[11]);
    float fcd = fminf(acc[12], acc[13]), fef = fminf(acc[14], acc[15]);
    float tmin_f = fminf(fminf(fminf(f01, f23), fminf(f45, f67)),
                         fminf(fminf(f89, fab), fminf(fcd, fef)));
    if (tmin_f < th_f) {
      const u32 cb_idx = (u32)(nt * 64 + wc * 32 + 4 * h);
      u32 tk[16];
#pragma unroll
      for (int j = 0; j < 16; ++j) {
        u32 off = (u32)((j & 3) + 8 * (j >> 2));
        tk[j] = (__float_as_uint(acc[j]) & 0xFFFFF000u) + cb_idx + off;  // low12 clear
      }
      // bitonic sort tk ascending (all indices compile-time)
#pragma unroll
      for (int k = 2; k <= 16; k <<= 1)
#pragma unroll
        for (int j = k >> 1; j > 0; j >>= 1)
#pragma unroll
          for (int i = 0; i < 16; ++i) {
            int l = i ^ j;
            if (l > i) {
              bool asc = ((i & k) == 0);
              u32 a = tk[i], b = tk[l];
              u32 lo = a < b ? a : b, hi = a < b ? b : a;
              tk[i] = asc ? lo : hi;
              tk[l] = asc ? hi : lo;
            }
          }
      // merge in place: sd[i] = min(sd[i], tk[15-i]) is bitonic; then clean
#pragma unroll
      for (int i = 0; i < 16; ++i) {
        u32 b = tk[15 - i];
        sd[i] = sd[i] < b ? sd[i] : b;
      }
#pragma unroll
      for (int j = 8; j > 0; j >>= 1)
#pragma unroll
        for (int i = 0; i < 16; ++i) {
          int l = i ^ j;
          if (l > i) {
            u32 a = sd[i], b = sd[l];
            sd[i] = a < b ? a : b;
            sd[l] = a < b ? b : a;
          }
        }
      th_f = __uint_as_float(sd[15] & 0xFFFFF000u);
    }
    __syncthreads();  // staged next buf ready; reads of cur complete
  }

  // dump per-thread lists, then 4-way merge per row -> fsn[row][slice*24..+24]
  u32* md = (u32*)smem;
  {
    int b = tid * 16;
#pragma unroll
    for (int t = 0; t < 16; ++t) md[b + t] = sd[t];
  }
  __syncthreads();
  if (tid < 64) {
    const int r = tid;                 // row within block (wq*32 + qcol)
    const int rwq = r >> 5, rl = r & 31;
    const u32* L[4];
#pragma unroll
    for (int wcc = 0; wcc < 2; ++wcc)
#pragma unroll
      for (int hh = 0; hh < 2; ++hh)
        L[wcc * 2 + hh] = md + (size_t)((rwq * 2 + wcc) * 64 + hh * 32 + rl) * 16;
    int p0 = 0, p1 = 0, p2 = 0, p3 = 0;
    size_t ob = (size_t)(grow0 + r) * 96 + (size_t)slice * 24;
    for (int t = 0; t < 24; ++t) {
      u32 k0 = (p0 < 16) ? L[0][p0] : 0xFFFFFFFFu;
      u32 k1 = (p1 < 16) ? L[1][p1] : 0xFFFFFFFFu;
      u32 k2 = (p2 < 16) ? L[2][p2] : 0xFFFFFFFFu;
      u32 k3 = (p3 < 16) ? L[3][p3] : 0xFFFFFFFFu;
      bool a01 = k0 <= k1; u32 kA = a01 ? k0 : k1;
      bool a23 = k2 <= k3; u32 kB = a23 ? k2 : k3;
      bool ab = kA <= kB;  u32 km = ab ? kA : kB;
      fsn[ob + t] = (u16)(cslice0 + (km & 0xFFFu));
      int win = ab ? (a01 ? 0 : 1) : (a23 ? 2 : 3);
      p0 += (win == 0); p1 += (win == 1); p2 += (win == 2); p3 += (win == 3);
    }
  }
}

// ---------------- RESCORE: exact no-FMA chain on 96 cands/row ---------------
// 2 rows/block x 96 threads; depth-4 prefetch (16 float4 in flight) hides the
// L2 gather latency. The ascending-k add chain (data-dependent on s) is
// order-preserved -> scores bit-identical to the verified realization.
__global__ __launch_bounds__(192) void rescore_kernel(const float* __restrict__ train,
                                                      const float* __restrict__ feat,
                                                      const float* __restrict__ rn,
                                                      const u16* __restrict__ fsn,
                                                      int* __restrict__ nbrt,
                                                      int* __restrict__ nbrq) {
  __shared__ __align__(16) float rowf[2][132];
  __shared__ __align__(16) float sc[2][100];
  __shared__ __align__(16) int sidx[2][100];
  const int tid = threadIdx.x;
  const int sub = (tid >= 96) ? 1 : 0;
  const int t = tid - sub * 96;
  const int row = blockIdx.x * 2 + sub;  // 10240 blocks -> 20480
  const float* src = (row < NTR) ? (train + (size_t)row * DF) : (feat + (size_t)(row - NTR) * DF);
  for (int i = t; i < DF; i += 96) rowf[sub][i] = src[i];
  __syncthreads();
  {
    int ci = (int)fsn[(size_t)row * 96 + t];
    if (ci >= NTR) ci = NTR - 1;  // defensive (bug -> absmax, not fault)
    const float* tv = train + (size_t)ci * DF;
    // depth-4 chunk prefetch: chunks 0..3 in flight; consume ch, issue ch+4
    float4 B0[4], B1[4], B2[4], B3[4];
#pragma unroll
    for (int p = 0; p < 4; ++p) {
      const float* cp = tv + p * 16;
      float4* Bp = (p == 0) ? B0 : (p == 1) ? B1 : (p == 2) ? B2 : B3;
      Bp[0] = *(const float4*)(cp + 0);
      Bp[1] = *(const float4*)(cp + 4);
      Bp[2] = *(const float4*)(cp + 8);
      Bp[3] = *(const float4*)(cp + 12);
    }
    float s = 0.0f;
#pragma unroll
    for (int ch = 0; ch < 8; ++ch) {
      float4* B = ((ch & 3) == 0) ? B0 : ((ch & 3) == 1) ? B1 : ((ch & 3) == 2) ? B2 : B3;
      float4 q0 = *(const float4*)&rowf[sub][ch * 16 + 0];
      float4 q1 = *(const float4*)&rowf[sub][ch * 16 + 4];
      float4 q2 = *(const float4*)&rowf[sub][ch * 16 + 8];
      float4 q3 = *(const float4*)&rowf[sub][ch * 16 + 12];
      float4 b0 = B[0], b1 = B[1], b2 = B[2], b3 = B[3];
      // strict ascending-k chain (order fixed by the dependence on s)
      s = s + mulr(q0.x, b0.x); s = s + mulr(q0.y, b0.y);
      s = s + mulr(q0.z, b0.z); s = s + mulr(q0.w, b0.w);
      s = s + mulr(q1.x, b1.x); s = s + mulr(q1.y, b1.y);
      s = s + mulr(q1.z, b1.z); s = s + mulr(q1.w, b1.w);
      s = s + mulr(q2.x, b2.x); s = s + mulr(q2.y, b2.y);
      s = s + mulr(q2.z, b2.z); s = s + mulr(q2.w, b2.w);
      s = s + mulr(q3.x, b3.x); s = s + mulr(q3.y, b3.y);
      s = s + mulr(q3.z, b3.z); s = s + mulr(q3.w, b3.w);
      if (ch < 4) {  // issue chunk ch+4 into the slot just freed
        const float* cp = tv + (ch + 4) * 16;
        B[0] = *(const float4*)(cp + 0);
        B[1] = *(const float4*)(cp + 4);
        B[2] = *(const float4*)(cp + 8);
        B[3] = *(const float4*)(cp + 12);
      }
    }
    float t1 = rn[row] + rn[ci];
    sc[sub][t] = t1 - 2.0f * s;
    sidx[sub][t] = ci;
  }
  __syncthreads();
  {
    float dm = sc[sub][t];
    int im = sidx[sub][t];
    int rank = 0;
#pragma unroll 4
    for (int i = 0; i < 96; i += 4) {
      float4 d4 = *(const float4*)&sc[sub][i];
      int4 i4 = *(const int4*)&sidx[sub][i];
      rank += (d4.x < dm || (d4.x == dm && i4.x < im));
      rank += (d4.y < dm || (d4.y == dm && i4.y < im));
      rank += (d4.z < dm || (d4.z == dm && i4.z < im));
      rank += (d4.w < dm || (d4.w == dm && i4.w < im));
    }
    if (rank < 20) {
      int* outp = (row < NTR) ? (nbrt + (size_t)row * 20) : (nbrq + (size_t)(row - NTR) * 20);
      outp[rank] = im;
    }
  }
}

// ---------------- label-count histograms (k=10 and k=20) ----------------
__global__ __launch_bounds__(256) void hist_kernel(const int* __restrict__ labels,
                                                   const int* __restrict__ nbrt,
                                                   int* __restrict__ ghist) {
  __shared__ int h[2432];
  int tid = threadIdx.x;
  for (int i = tid; i < 2432; i += 256) h[i] = 0;
  __syncthreads();
  int row = blockIdx.x * 256 + tid;  // 64 blocks -> 16384
  int nb[20];
#pragma unroll
  for (int j = 0; j < 20; ++j) nb[j] = nbrt[(size_t)row * 20 + j];
  int cnt[NCL];
#pragma unroll
  for (int c = 0; c < NCL; ++c) cnt[c] = 0;
#pragma unroll
  for (int j = 0; j < 10; ++j) {
    const int* lr = labels + (size_t)nb[j] * NCL;
#pragma unroll
    for (int c = 0; c < NCL; ++c) cnt[c] += lr[c];
  }
  const int* myl = labels + (size_t)row * NCL;
  int my[NCL];
#pragma unroll
  for (int c = 0; c < NCL; ++c) my[c] = myl[c];
#pragma unroll
  for (int c = 0; c < NCL; ++c)
    atomicAdd(&h[((0 * 2 + my[c]) * NCL + c) * 32 + cnt[c]], 1);
#pragma unroll
  for (int j = 10; j < 20; ++j) {
    const int* lr = labels + (size_t)nb[j] * NCL;
#pragma unroll
    for (int c = 0; c < NCL; ++c) cnt[c] += lr[c];
  }
#pragma unroll
  for (int c = 0; c < NCL; ++c)
    atomicAdd(&h[((1 * 2 + my[c]) * NCL + c) * 32 + cnt[c]], 1);
  __syncthreads();
  for (int i = tid; i < 2432; i += 256) {
    int v = h[i];
    if (v) atomicAdd(&ghist[i], v);
  }
}

// ---------------- conditional tables + priors ----------------
__global__ __launch_bounds__(256) void prep_kernel(const int* __restrict__ ghist,
                                                   float* __restrict__ cond,
                                                   float* __restrict__ prior) {
  __shared__ int cpos[NCL];
  int tid = threadIdx.x;
  if (tid < NCL) {
    int s = 0;
    for (int d = 0; d < 32; ++d) s += ghist[((0 * 2 + 1) * NCL + tid) * 32 + d];
    cpos[tid] = s;
    prior[tid] = (1.0f + (float)s) / (2.0f + (float)NTR);
  }
  __syncthreads();
  for (int i = tid; i < 2432; i += 256) {
    int cc = (i >> 5) % NCL;
    int pos = ((i >> 5) / NCL) & 1;
    int ki = i / (2 * NCL * 32);
    int k = ki ? 20 : 10;
    float num = 1.0f + (float)ghist[i];
    float den = (float)(k + 1) + (float)(pos ? cpos[cc] : (NTR - cpos[cc]));
    cond[i] = num / den;
  }
}

// ---------------- posterior output ----------------
__global__ __launch_bounds__(256) void out_kernel(const int* __restrict__ labels,
                                                  const int* __restrict__ nbrq,
                                                  const float* __restrict__ cond,
                                                  const float* __restrict__ prior,
                                                  float* __restrict__ out) {
  int q = blockIdx.x * 256 + threadIdx.x;  // 16 blocks -> 4096
  int nb[20];
#pragma unroll
  for (int j = 0; j < 20; ++j) nb[j] = nbrq[(size_t)q * 20 + j];
  int cnt[NCL], d10[NCL];
#pragma unroll
  for (int c = 0; c < NCL; ++c) cnt[c] = 0;
#pragma unroll
  for (int j = 0; j < 10; ++j) {
    const int* lr = labels + (size_t)nb[j] * NCL;
#pragma unroll
    for (int c = 0; c < NCL; ++c) cnt[c] += lr[c];
  }
#pragma unroll
  for (int c = 0; c < NCL; ++c) d10[c] = cnt[c];
#pragma unroll
  for (int j = 10; j < 20; ++j) {
    const int* lr = labels + (size_t)nb[j] * NCL;
#pragma unroll
    for (int c = 0; c < NCL; ++c) cnt[c] += lr[c];
  }
#pragma unroll
  for (int ki = 0; ki < 2; ++ki) {
#pragma unroll
    for (int c = 0; c < NCL; ++c) {
      int delta = ki ? cnt[c] : d10[c];
      float pr = prior[c];
      float pt = pr * cond[((ki * 2 + 1) * NCL + c) * 32 + delta];
      float pf = (1.0f - pr) * cond[((ki * 2 + 0) * NCL + c) * 32 + delta];
      out[((size_t)ki * NQR + q) * NCL + c] = pt / (pt + pf);
    }
  }
}

extern "C" void kernel_launch(void* const* d_in, const int* in_sizes, int n_in,
                              void* d_out, int out_size, void* d_ws, size_t ws_size,
                              hipStream_t stream) {
  const float* feat = (const float*)d_in[0];     // [4096,128]
  const float* train = (const float*)d_in[1];    // [16384,128]
  const int* labels = (const int*)d_in[2];       // [16384,19]
  float* out = (float*)d_out;                    // [2,4096,19]
  if (ws_size < WS_NEEDED) return;               // loud failure via poisoned output
  char* w = (char*)d_ws;
  float* rn = (float*)(w + OFF_RN);
  u16* qext = (u16*)(w + OFF_QEXT);
  u16* cext = (u16*)(w + OFF_CEXT);
  u16* fsn = (u16*)(w + OFF_FSN);
  int* nbrt = (int*)(w + OFF_NBRT);
  int* nbrq = (int*)(w + OFF_NBRQ);
  int* ghist = (int*)(w + OFF_HIST);
  float* cond = (float*)(w + OFF_COND);
  float* prior = (float*)(w + OFF_PRIOR);

  hipMemsetAsync(ghist, 0, 2432 * 4, stream);
  norms_kernel<<<80, 256, 0, stream>>>(train, feat, rn);
  ext_kernel<<<10240, 256, 0, stream>>>(train, feat, rn, qext, cext);
  filter_kernel<<<1280, 256, 0, stream>>>(qext, cext, fsn);
  rescore_kernel<<<10240, 192, 0, stream>>>(train, feat, rn, fsn, nbrt, nbrq);
  hist_kernel<<<64, 256, 0, stream>>>(labels, nbrt, ghist);
  prep_kernel<<<1, 256, 0, stream>>>(ghist, cond, prior);
  out_kernel<<<16, 256, 0, stream>>>(labels, nbrq, cond, prior, out);
}

// Round 20
// 377.907 us; speedup vs baseline: 1.1290x; 1.1290x over previous
//
#include <hip/hip_runtime.h>
#include <cstdint>
#include <cstddef>

#define NTR 16384
#define NQR 4096
#define NROW 20480
#define DF  128
#define NCL 19

typedef unsigned short u16;
typedef unsigned int u32;
typedef __attribute__((ext_vector_type(8))) short bf16x8;
typedef __attribute__((ext_vector_type(16))) float f32x16;

// ---- workspace layout (bytes) ----
#define OFF_RN    (size_t)0                  // float[20480]
#define OFF_QEXT  (size_t)81920              // u16[20480][144]
#define OFF_CEXT  (size_t)5980160            // u16[16384][144] (negated + hb dims)
#define OFF_FSN   (size_t)10698752           // u16[20480][64]
#define OFF_NBRT  (size_t)18563072           // int[16384][20]
#define OFF_NBRQ  (size_t)19873792           // int[4096][20]
#define OFF_HIST  (size_t)20201472           // int[2][2][19][32]
#define OFF_COND  (size_t)20211200           // float[2][2][19][32]
#define OFF_PRIOR (size_t)20220928           // float[19]
#define WS_NEEDED (size_t)20221008

// separately-rounded multiply (asm barrier blocks mul+add -> fma contraction)
__device__ __forceinline__ float mulr(float a, float b) {
  float m = a * b;
  asm volatile("" : "+v"(m));
  return m;
}

__device__ __forceinline__ u16 bf16_rne(float x) {
  union { float f; unsigned u; } v; v.f = x;
  unsigned r = (v.u + 0x7fffu + ((v.u >> 16) & 1u)) >> 16;
  return (u16)r;
}
__device__ __forceinline__ float bf16_f32(u16 h) {
  union { unsigned u; float f; } v; v.u = ((unsigned)h) << 16;
  return v.f;
}

__device__ __forceinline__ void gload_lds16(const void* g, void* lds) {
  __builtin_amdgcn_global_load_lds(
      (const __attribute__((address_space(1))) unsigned int*)g,
      (__attribute__((address_space(3))) unsigned int*)lds, 16, 0, 0);
}

// ---------------- row norms: exact reference realization (no FMA) ------------
__global__ __launch_bounds__(256) void norms_kernel(const float* __restrict__ train,
                                                    const float* __restrict__ feat,
                                                    float* __restrict__ rn) {
  int i = blockIdx.x * 256 + threadIdx.x;  // 80 blocks -> 20480
  const float* src = (i < NTR) ? (train + (size_t)i * DF) : (feat + (size_t)(i - NTR) * DF);
  float s = 0.0f;
  for (int k = 0; k < DF; ++k) {
    float x = src[k];
    s = s + mulr(x, x);
  }
  rn[i] = s;
}

// ---------------- ext: bf16 rows + metric K-extension (r12 form) -------------
// qext[row][144]: [bf16(x_k)]*128, dim128=1.0, dim129=1.0, rest 0
// cext[c][144]:   [bf16(-x_k)]*128, dim128=hb_hi, dim129=hb_lo, rest 0
// where hb = 0.5*rn[c] + 256  ->  mfma(C,Q) = 256 + hb - dot  (positive metric)
__global__ __launch_bounds__(256) void ext_kernel(const float* __restrict__ train,
                                                  const float* __restrict__ feat,
                                                  const float* __restrict__ rn,
                                                  u16* __restrict__ qext,
                                                  u16* __restrict__ cext) {
  int row = blockIdx.x * 2 + (threadIdx.x >> 7);  // 10240 blocks -> 20480
  int k = threadIdx.x & 127;
  const float* srcp = (row < NTR) ? (train + (size_t)row * DF) : (feat + (size_t)(row - NTR) * DF);
  float x = srcp[k];
  u16 b = bf16_rne(x);
  qext[(size_t)row * 144 + k] = b;
  if (row < NTR) cext[(size_t)row * 144 + k] = (u16)(b ^ 0x8000u);
  if (k < 16) {
    qext[(size_t)row * 144 + 128 + k] = (k < 2) ? (u16)0x3F80 : (u16)0;
    if (row < NTR) {
      float hbf = 0.5f * rn[row] + 256.0f;
      u16 hi = bf16_rne(hbf);
      u16 lo = bf16_rne(hbf - bf16_f32(hi));
      cext[(size_t)row * 144 + 128 + k] = (k == 0) ? hi : ((k == 1) ? lo : (u16)0);
    }
  }
}

// ---------------- FILTER: swapped 32x32x16 MFMA, 1 q-subtile/wave ------------
// r20 = r12's exact inner config (best measured): 4 slices of 4096 cands,
// grid 1280, 64 tiles/block, dbuf 36.9KB, 12-bit packed keys, bitonic merge.
// Output: per-slice top-16 (EXACT at stream level: merged top-16 of 4x16
// stream lists can't lose a slice-top-16 member) -> fsn 64 cands/row.
__global__ __launch_bounds__(256, 4) void filter_kernel(const u16* __restrict__ qext,
                                                        const u16* __restrict__ cext,
                                                        u16* __restrict__ fsn) {
  __shared__ __align__(16) char smem[36864];  // cbuf[2]:16KB, hbuf[2]:2KB
  const int bid = blockIdx.x;
  const int slice = bid & 3, rowblk = bid >> 2;
  const int grow0 = rowblk * 64;
  const int cslice0 = slice * 4096;
  const int tid = threadIdx.x;
  const int wave = tid >> 6, lane = tid & 63;
  const int wq = wave >> 1, wc = wave & 1;
  const int l31 = lane & 31, h = lane >> 5;
  const char* qb = (const char*)qext;
  const char* cbg = (const char*)cext;

  // q fragments in registers: 9 ksteps for this wave's 32-row q-subtile
  bf16x8 qf[9];
  const int qrow = grow0 + wq * 32 + l31;
#pragma unroll
  for (int ks = 0; ks < 8; ++ks)
    qf[ks] = *(const bf16x8*)(qb + (size_t)qrow * 288 + ks * 32 + h * 16);
  qf[8] = *(const bf16x8*)(qb + (size_t)qrow * 288 + 256 + h * 16);

  u32 sd[16];
#pragma unroll
  for (int t = 0; t < 16; ++t) sd[t] = 0x7F7FFFFFu;
  float th_f = __uint_as_float(0x7F7FF000u);

  // incremental per-thread staging source pointers (advance 64*288 B per tile)
  const char* srcA[4];
#pragma unroll
  for (int j = 0; j < 4; ++j) {
    int I = wave + 4 * j;
    int G = I * 64 + lane;
    int r = G >> 4, g = G & 15;
    srcA[j] = cbg + (size_t)(cslice0 + r) * 288 + ((g << 4) ^ ((r & 7) << 4));
  }
  const char* srcH = nullptr;
  if (wave < 2) {
    int GG = wave * 64 + lane;
    int r = GG >> 1, half = GG & 1;
    srcH = cbg + (size_t)(cslice0 + r) * 288 + 256 + half * 16;
  }

  auto STAGE = [&](int buf) {
    char* cb = smem + buf * 16384;
#pragma unroll
    for (int j = 0; j < 4; ++j) {
      int I = wave + 4 * j;
      gload_lds16(srcA[j], cb + I * 1024);
      srcA[j] += 64 * 288;
    }
    if (wave < 2) {
      gload_lds16(srcH, smem + 32768 + buf * 2048 + wave * 1024);
      srcH += 64 * 288;
    }
  };

  STAGE(0);
  __syncthreads();

  const int crow = wc * 32 + l31;
  for (int nt = 0; nt < 64; ++nt) {
    const int cur = nt & 1;
    if (nt < 63) STAGE(cur ^ 1);

    const char* cbp = smem + cur * 16384 + crow * 256;
    const char* hbp = smem + 32768 + cur * 2048 + crow * 32 + h * 16;
    f32x16 acc = {0.f,0.f,0.f,0.f,0.f,0.f,0.f,0.f,0.f,0.f,0.f,0.f,0.f,0.f,0.f,0.f};
#pragma unroll
    for (int ks = 0; ks < 8; ++ks) {
      bf16x8 cf = *(const bf16x8*)(cbp + ((ks * 32 + h * 16) ^ ((crow & 7) << 4)));
      acc = __builtin_amdgcn_mfma_f32_32x32x16_bf16(cf, qf[ks], acc, 0, 0, 0);
    }
    {
      bf16x8 cf = *(const bf16x8*)hbp;
      acc = __builtin_amdgcn_mfma_f32_32x32x16_bf16(cf, qf[8], acc, 0, 0, 0);
    }

    // ---- float guard first (saves key packing on non-triggered tiles) ----
    float f01 = fminf(acc[0], acc[1]),   f23 = fminf(acc[2], acc[3]);
    float f45 = fminf(acc[4], acc[5]),   f67 = fminf(acc[6], acc[7]);
    float f89 = fminf(acc[8], acc[9]),   fab = fminf(acc[10], acc[11]);
    float fcd = fminf(acc[12], acc[13]), fef = fminf(acc[14], acc[15]);
    float tmin_f = fminf(fminf(fminf(f01, f23), fminf(f45, f67)),
                         fminf(fminf(f89, fab), fminf(fcd, fef)));
    if (tmin_f < th_f) {
      const u32 cb_idx = (u32)(nt * 64 + wc * 32 + 4 * h);
      u32 tk[16];
#pragma unroll
      for (int j = 0; j < 16; ++j) {
        u32 off = (u32)((j & 3) + 8 * (j >> 2));
        tk[j] = (__float_as_uint(acc[j]) & 0xFFFFF000u) + cb_idx + off;  // low12 clear
      }
      // bitonic sort tk ascending (all indices compile-time)
#pragma unroll
      for (int k = 2; k <= 16; k <<= 1)
#pragma unroll
        for (int j = k >> 1; j > 0; j >>= 1)
#pragma unroll
          for (int i = 0; i < 16; ++i) {
            int l = i ^ j;
            if (l > i) {
              bool asc = ((i & k) == 0);
              u32 a = tk[i], b = tk[l];
              u32 lo = a < b ? a : b, hi = a < b ? b : a;
              tk[i] = asc ? lo : hi;
              tk[l] = asc ? hi : lo;
            }
          }
      // merge in place: sd[i] = min(sd[i], tk[15-i]) is bitonic; then clean
#pragma unroll
      for (int i = 0; i < 16; ++i) {
        u32 b = tk[15 - i];
        sd[i] = sd[i] < b ? sd[i] : b;
      }
#pragma unroll
      for (int j = 8; j > 0; j >>= 1)
#pragma unroll
        for (int i = 0; i < 16; ++i) {
          int l = i ^ j;
          if (l > i) {
            u32 a = sd[i], b = sd[l];
            sd[i] = a < b ? a : b;
            sd[l] = a < b ? b : a;
          }
        }
      th_f = __uint_as_float(sd[15] & 0xFFFFF000u);
    }
    __syncthreads();  // staged next buf ready; reads of cur complete
  }

  // dump per-thread lists, then 4-way merge per row -> fsn[row][slice*16..+16]
  u32* md = (u32*)smem;
  {
    int b = tid * 16;
#pragma unroll
    for (int t = 0; t < 16; ++t) md[b + t] = sd[t];
  }
  __syncthreads();
  if (tid < 64) {
    const int r = tid;                 // row within block (wq*32 + qcol)
    const int rwq = r >> 5, rl = r & 31;
    const u32* L[4];
#pragma unroll
    for (int wcc = 0; wcc < 2; ++wcc)
#pragma unroll
      for (int hh = 0; hh < 2; ++hh)
        L[wcc * 2 + hh] = md + (size_t)((rwq * 2 + wcc) * 64 + hh * 32 + rl) * 16;
    int p0 = 0, p1 = 0, p2 = 0, p3 = 0;
    size_t ob = (size_t)(grow0 + r) * 64 + (size_t)slice * 16;
    for (int t = 0; t < 16; ++t) {
      u32 k0 = L[0][p0], k1 = L[1][p1], k2 = L[2][p2], k3 = L[3][p3];
      bool a01 = k0 <= k1; u32 kA = a01 ? k0 : k1;
      bool a23 = k2 <= k3; u32 kB = a23 ? k2 : k3;
      bool ab = kA <= kB;  u32 km = ab ? kA : kB;
      fsn[ob + t] = (u16)(cslice0 + (km & 0xFFFu));
      int win = ab ? (a01 ? 0 : 1) : (a23 ? 2 : 3);
      p0 += (win == 0); p1 += (win == 1); p2 += (win == 2); p3 += (win == 3);
    }
  }
}

// ---------------- RESCORE: exact no-FMA chain on 64 cands/row ---------------
// 4 rows/block x 64 threads; depth-4 prefetch (16 float4 in flight) hides the
// L2 gather latency. The ascending-k add chain (data-dependent on s) is
// order-preserved -> scores bit-identical to the verified realization.
__global__ __launch_bounds__(256) void rescore_kernel(const float* __restrict__ train,
                                                      const float* __restrict__ feat,
                                                      const float* __restrict__ rn,
                                                      const u16* __restrict__ fsn,
                                                      int* __restrict__ nbrt,
                                                      int* __restrict__ nbrq) {
  __shared__ __align__(16) float rowf[4][132];
  __shared__ __align__(16) float sc[4][68];
  __shared__ __align__(16) int sidx[4][68];
  const int tid = threadIdx.x;
  const int sub = tid >> 6;
  const int t = tid & 63;
  const int row = blockIdx.x * 4 + sub;  // 5120 blocks -> 20480
  const float* src = (row < NTR) ? (train + (size_t)row * DF) : (feat + (size_t)(row - NTR) * DF);
  for (int i = t; i < DF; i += 64) rowf[sub][i] = src[i];
  __syncthreads();
  {
    int ci = (int)fsn[(size_t)row * 64 + t];
    if (ci >= NTR) ci = NTR - 1;  // defensive (bug -> absmax, not fault)
    const float* tv = train + (size_t)ci * DF;
    // depth-4 chunk prefetch: chunks 0..3 in flight; consume ch, issue ch+4
    float4 B0[4], B1[4], B2[4], B3[4];
#pragma unroll
    for (int p = 0; p < 4; ++p) {
      const float* cp = tv + p * 16;
      float4* Bp = (p == 0) ? B0 : (p == 1) ? B1 : (p == 2) ? B2 : B3;
      Bp[0] = *(const float4*)(cp + 0);
      Bp[1] = *(const float4*)(cp + 4);
      Bp[2] = *(const float4*)(cp + 8);
      Bp[3] = *(const float4*)(cp + 12);
    }
    float s = 0.0f;
#pragma unroll
    for (int ch = 0; ch < 8; ++ch) {
      float4* B = ((ch & 3) == 0) ? B0 : ((ch & 3) == 1) ? B1 : ((ch & 3) == 2) ? B2 : B3;
      float4 q0 = *(const float4*)&rowf[sub][ch * 16 + 0];
      float4 q1 = *(const float4*)&rowf[sub][ch * 16 + 4];
      float4 q2 = *(const float4*)&rowf[sub][ch * 16 + 8];
      float4 q3 = *(const float4*)&rowf[sub][ch * 16 + 12];
      float4 b0 = B[0], b1 = B[1], b2 = B[2], b3 = B[3];
      // strict ascending-k chain (order fixed by the dependence on s)
      s = s + mulr(q0.x, b0.x); s = s + mulr(q0.y, b0.y);
      s = s + mulr(q0.z, b0.z); s = s + mulr(q0.w, b0.w);
      s = s + mulr(q1.x, b1.x); s = s + mulr(q1.y, b1.y);
      s = s + mulr(q1.z, b1.z); s = s + mulr(q1.w, b1.w);
      s = s + mulr(q2.x, b2.x); s = s + mulr(q2.y, b2.y);
      s = s + mulr(q2.z, b2.z); s = s + mulr(q2.w, b2.w);
      s = s + mulr(q3.x, b3.x); s = s + mulr(q3.y, b3.y);
      s = s + mulr(q3.z, b3.z); s = s + mulr(q3.w, b3.w);
      if (ch < 4) {  // issue chunk ch+4 into the slot just freed
        const float* cp = tv + (ch + 4) * 16;
        B[0] = *(const float4*)(cp + 0);
        B[1] = *(const float4*)(cp + 4);
        B[2] = *(const float4*)(cp + 8);
        B[3] = *(const float4*)(cp + 12);
      }
    }
    float t1 = rn[row] + rn[ci];
    sc[sub][t] = t1 - 2.0f * s;
    sidx[sub][t] = ci;
  }
  __syncthreads();
  {
    float dm = sc[sub][t];
    int im = sidx[sub][t];
    int rank = 0;
#pragma unroll 4
    for (int i = 0; i < 64; i += 4) {
      float4 d4 = *(const float4*)&sc[sub][i];
      int4 i4 = *(const int4*)&sidx[sub][i];
      rank += (d4.x < dm || (d4.x == dm && i4.x < im));
      rank += (d4.y < dm || (d4.y == dm && i4.y < im));
      rank += (d4.z < dm || (d4.z == dm && i4.z < im));
      rank += (d4.w < dm || (d4.w == dm && i4.w < im));
    }
    if (rank < 20) {
      int* outp = (row < NTR) ? (nbrt + (size_t)row * 20) : (nbrq + (size_t)(row - NTR) * 20);
      outp[rank] = im;
    }
  }
}

// ---------------- label-count histograms (k=10 and k=20) ----------------
__global__ __launch_bounds__(256) void hist_kernel(const int* __restrict__ labels,
                                                   const int* __restrict__ nbrt,
                                                   int* __restrict__ ghist) {
  __shared__ int h[2432];
  int tid = threadIdx.x;
  for (int i = tid; i < 2432; i += 256) h[i] = 0;
  __syncthreads();
  int row = blockIdx.x * 256 + tid;  // 64 blocks -> 16384
  int nb[20];
#pragma unroll
  for (int j = 0; j < 20; ++j) nb[j] = nbrt[(size_t)row * 20 + j];
  int cnt[NCL];
#pragma unroll
  for (int c = 0; c < NCL; ++c) cnt[c] = 0;
#pragma unroll
  for (int j = 0; j < 10; ++j) {
    const int* lr = labels + (size_t)nb[j] * NCL;
#pragma unroll
    for (int c = 0; c < NCL; ++c) cnt[c] += lr[c];
  }
  const int* myl = labels + (size_t)row * NCL;
  int my[NCL];
#pragma unroll
  for (int c = 0; c < NCL; ++c) my[c] = myl[c];
#pragma unroll
  for (int c = 0; c < NCL; ++c)
    atomicAdd(&h[((0 * 2 + my[c]) * NCL + c) * 32 + cnt[c]], 1);
#pragma unroll
  for (int j = 10; j < 20; ++j) {
    const int* lr = labels + (size_t)nb[j] * NCL;
#pragma unroll
    for (int c = 0; c < NCL; ++c) cnt[c] += lr[c];
  }
#pragma unroll
  for (int c = 0; c < NCL; ++c)
    atomicAdd(&h[((1 * 2 + my[c]) * NCL + c) * 32 + cnt[c]], 1);
  __syncthreads();
  for (int i = tid; i < 2432; i += 256) {
    int v = h[i];
    if (v) atomicAdd(&ghist[i], v);
  }
}

// ---------------- conditional tables + priors ----------------
__global__ __launch_bounds__(256) void prep_kernel(const int* __restrict__ ghist,
                                                   float* __restrict__ cond,
                                                   float* __restrict__ prior) {
  __shared__ int cpos[NCL];
  int tid = threadIdx.x;
  if (tid < NCL) {
    int s = 0;
    for (int d = 0; d < 32; ++d) s += ghist[((0 * 2 + 1) * NCL + tid) * 32 + d];
    cpos[tid] = s;
    prior[tid] = (1.0f + (float)s) / (2.0f + (float)NTR);
  }
  __syncthreads();
  for (int i = tid; i < 2432; i += 256) {
    int cc = (i >> 5) % NCL;
    int pos = ((i >> 5) / NCL) & 1;
    int ki = i / (2 * NCL * 32);
    int k = ki ? 20 : 10;
    float num = 1.0f + (float)ghist[i];
    float den = (float)(k + 1) + (float)(pos ? cpos[cc] : (NTR - cpos[cc]));
    cond[i] = num / den;
  }
}

// ---------------- posterior output ----------------
__global__ __launch_bounds__(256) void out_kernel(const int* __restrict__ labels,
                                                  const int* __restrict__ nbrq,
                                                  const float* __restrict__ cond,
                                                  const float* __restrict__ prior,
                                                  float* __restrict__ out) {
  int q = blockIdx.x * 256 + threadIdx.x;  // 16 blocks -> 4096
  int nb[20];
#pragma unroll
  for (int j = 0; j < 20; ++j) nb[j] = nbrq[(size_t)q * 20 + j];
  int cnt[NCL], d10[NCL];
#pragma unroll
  for (int c = 0; c < NCL; ++c) cnt[c] = 0;
#pragma unroll
  for (int j = 0; j < 10; ++j) {
    const int* lr = labels + (size_t)nb[j] * NCL;
#pragma unroll
    for (int c = 0; c < NCL; ++c) cnt[c] += lr[c];
  }
#pragma unroll
  for (int c = 0; c < NCL; ++c) d10[c] = cnt[c];
#pragma unroll
  for (int j = 10; j < 20; ++j) {
    const int* lr = labels + (size_t)nb[j] * NCL;
#pragma unroll
    for (int c = 0; c < NCL; ++c) cnt[c] += lr[c];
  }
#pragma unroll
  for (int ki = 0; ki < 2; ++ki) {
#pragma unroll
    for (int c = 0; c < NCL; ++c) {
      int delta = ki ? cnt[c] : d10[c];
      float pr = prior[c];
      float pt = pr * cond[((ki * 2 + 1) * NCL + c) * 32 + delta];
      float pf = (1.0f - pr) * cond[((ki * 2 + 0) * NCL + c) * 32 + delta];
      out[((size_t)ki * NQR + q) * NCL + c] = pt / (pt + pf);
    }
  }
}

extern "C" void kernel_launch(void* const* d_in, const int* in_sizes, int n_in,
                              void* d_out, int out_size, void* d_ws, size_t ws_size,
                              hipStream_t stream) {
  const float* feat = (const float*)d_in[0];     // [4096,128]
  const float* train = (const float*)d_in[1];    // [16384,128]
  const int* labels = (const int*)d_in[2];       // [16384,19]
  float* out = (float*)d_out;                    // [2,4096,19]
  if (ws_size < WS_NEEDED) return;               // loud failure via poisoned output
  char* w = (char*)d_ws;
  float* rn = (float*)(w + OFF_RN);
  u16* qext = (u16*)(w + OFF_QEXT);
  u16* cext = (u16*)(w + OFF_CEXT);
  u16* fsn = (u16*)(w + OFF_FSN);
  int* nbrt = (int*)(w + OFF_NBRT);
  int* nbrq = (int*)(w + OFF_NBRQ);
  int* ghist = (int*)(w + OFF_HIST);
  float* cond = (float*)(w + OFF_COND);
  float* prior = (float*)(w + OFF_PRIOR);

  hipMemsetAsync(ghist, 0, 2432 * 4, stream);
  norms_kernel<<<80, 256, 0, stream>>>(train, feat, rn);
  ext_kernel<<<10240, 256, 0, stream>>>(train, feat, rn, qext, cext);
  filter_kernel<<<1280, 256, 0, stream>>>(qext, cext, fsn);
  rescore_kernel<<<5120, 256, 0, stream>>>(train, feat, rn, fsn, nbrt, nbrq);
  hist_kernel<<<64, 256, 0, stream>>>(labels, nbrt, ghist);
  prep_kernel<<<1, 256, 0, stream>>>(ghist, cond, prior);
  out_kernel<<<16, 256, 0, stream>>>(labels, nbrq, cond, prior, out);
}